// Round 1
// baseline (1218.235 us; speedup 1.0000x reference)
//
#include <hip/hip_runtime.h>
#include <hip/hip_bf16.h>
#include <stdint.h>

#define N_TOK 8192
#define H_DIM 1024
#define D_DIM 2048
#define NEXP  8

#define NSLOT      16384          // N_TOK * 2 routed slots
#define SHARED_ROW 16512          // NSLOT + 128 pad rows
#define HID_ROWS   24704          // SHARED_ROW + N_TOK

typedef __attribute__((ext_vector_type(8))) short          bf16x8;
typedef __attribute__((ext_vector_type(4))) float          f32x4;
typedef __attribute__((ext_vector_type(8))) unsigned short u16x8;

__device__ __forceinline__ unsigned short f2bf(float f) {
    union { float f; uint32_t u; } v; v.f = f;
    uint32_t r = v.u + 0x7fff + ((v.u >> 16) & 1);   // RNE
    return (unsigned short)(r >> 16);
}

__device__ __forceinline__ void gll16(const void* g, void* l) {
    __builtin_amdgcn_global_load_lds(
        (const __attribute__((address_space(1))) void*)g,
        (__attribute__((address_space(3))) void*)l, 16, 0, 0);
}

// ---------------- router: one wave per token ----------------
__global__ void k_router(const float* __restrict__ x, const float* __restrict__ gw,
                         int* __restrict__ tok_e, float* __restrict__ tok_w,
                         int* __restrict__ counts) {
    int l = threadIdx.x & 63;
    int n = blockIdx.x * 4 + (threadIdx.x >> 6);
    const float* xr = x + (size_t)n * H_DIM + l * 16;
    float acc[NEXP];
#pragma unroll
    for (int e = 0; e < NEXP; ++e) acc[e] = 0.f;
#pragma unroll
    for (int j = 0; j < 16; ++j) {
        float xv = xr[j];
        const float4* g4 = (const float4*)(gw + (size_t)(l * 16 + j) * NEXP);
        float4 g0 = g4[0], g1 = g4[1];
        acc[0] += xv * g0.x; acc[1] += xv * g0.y; acc[2] += xv * g0.z; acc[3] += xv * g0.w;
        acc[4] += xv * g1.x; acc[5] += xv * g1.y; acc[6] += xv * g1.z; acc[7] += xv * g1.w;
    }
#pragma unroll
    for (int off = 32; off >= 1; off >>= 1) {
#pragma unroll
        for (int e = 0; e < NEXP; ++e) acc[e] += __shfl_xor(acc[e], off);
    }
    if (l == 0) {
        int e0 = 0; float v0 = acc[0];
#pragma unroll
        for (int e = 1; e < NEXP; ++e) if (acc[e] > v0) { v0 = acc[e]; e0 = e; }
        int e1 = -1; float v1 = -1e30f;
#pragma unroll
        for (int e = 0; e < NEXP; ++e) if (e != e0 && acc[e] > v1) { v1 = acc[e]; e1 = e; }
        float t  = expf(v1 - v0);          // p1/p0
        float w1 = t / (1.f + t);
        float w0 = 1.f - w1;
        tok_e[2 * n]     = e0;  tok_e[2 * n + 1] = e1;
        tok_w[2 * n]     = w0;  tok_w[2 * n + 1] = w1;
        atomicAdd(&counts[e0], 1);
        atomicAdd(&counts[e1], 1);
    }
}

__global__ void k_scan(const int* __restrict__ counts, int* __restrict__ offs) {
    if (threadIdx.x == 0) {
        int s = 0;
        for (int e = 0; e < NEXP; ++e) { offs[e] = s; s += counts[e]; }
    }
}

__global__ void k_assign(const int* __restrict__ tok_e, const float* __restrict__ tok_w,
                         const int* __restrict__ offs, int* __restrict__ cursor,
                         int* __restrict__ slot_token, float* __restrict__ slot_weight) {
    int n = blockIdx.x * 256 + threadIdx.x;
#pragma unroll
    for (int k = 0; k < 2; ++k) {
        int e   = tok_e[2 * n + k];
        float w = tok_w[2 * n + k];
        int pos = atomicAdd(&cursor[e], 1);
        int s   = offs[e] + pos;
        slot_token[s]  = n;
        slot_weight[s] = w;
    }
}

// ---------------- f32 -> bf16 convert (x) ----------------
__global__ void k_cvt_x(const float* __restrict__ x, unsigned short* __restrict__ xb) {
    size_t i = ((size_t)blockIdx.x * 256 + threadIdx.x) * 8;
    float4 a = *(const float4*)(x + i);
    float4 b = *(const float4*)(x + i + 4);
    u16x8 o;
    o[0] = f2bf(a.x); o[1] = f2bf(a.y); o[2] = f2bf(a.z); o[3] = f2bf(a.w);
    o[4] = f2bf(b.x); o[5] = f2bf(b.y); o[6] = f2bf(b.z); o[7] = f2bf(b.w);
    *(u16x8*)(xb + i) = o;
}

// ---------------- transpose + convert: src[R][C] f32 -> dst[C][R] bf16 ----------------
__global__ void k_tconv(const float* __restrict__ src, unsigned short* __restrict__ dst,
                        int R, int C) {
    __shared__ float t[32][33];
    size_t mb = (size_t)blockIdx.z * (size_t)R * C;
    src += mb; dst += mb;
    int tx = threadIdx.x & 31, ty = threadIdx.x >> 5;   // ty 0..7
    int r0 = blockIdx.y * 32, c0 = blockIdx.x * 32;
#pragma unroll
    for (int i = 0; i < 4; ++i)
        t[ty + i * 8][tx] = src[(size_t)(r0 + ty + i * 8) * C + c0 + tx];
    __syncthreads();
#pragma unroll
    for (int i = 0; i < 4; ++i)
        dst[(size_t)(c0 + ty + i * 8) * R + r0 + tx] = f2bf(t[tx][ty + i * 8]);
}

// ---------------- grouped GEMM1: hid = silu(A@Wg) * (A@Wu), A gathered ----------------
// groups 0..7 routed (slot lists), group 8 = shared expert (identity rows)
__global__ __launch_bounds__(256) void k_gemm1(
    const unsigned short* __restrict__ xb,
    const unsigned short* __restrict__ wg_t, const unsigned short* __restrict__ wu_t,
    const unsigned short* __restrict__ wsg_t, const unsigned short* __restrict__ wsu_t,
    const int* __restrict__ counts, const int* __restrict__ offs,
    const int* __restrict__ slot_token, unsigned short* __restrict__ hid) {
    int g = blockIdx.z;
    int n_g, sbase, hbase;
    if (g < NEXP) { n_g = counts[g]; sbase = offs[g]; hbase = sbase; }
    else          { n_g = N_TOK;     sbase = 0;       hbase = SHARED_ROW; }
    int rt = blockIdx.y;
    if (rt * 128 >= n_g) return;
    int dt = blockIdx.x;

    const unsigned short* Bg = (g < NEXP) ? wg_t + (size_t)g * D_DIM * H_DIM : wsg_t;
    const unsigned short* Bu = (g < NEXP) ? wu_t + (size_t)g * D_DIM * H_DIM : wsu_t;

    __shared__ __attribute__((aligned(16))) char smem[48 * 1024];
    char* sA  = smem;
    char* sBg = smem + 16384;
    char* sBu = smem + 32768;

    int t = threadIdx.x;
    int w = t >> 6, l = t & 63;
    int lr8 = l >> 3, lc8 = l & 7;
    int swz = ((lc8 ^ lr8) << 4);   // inverse-swizzled global source byte (within 128B row)

    const char* aptr[4]; const char* bgptr[4]; const char* buptr[4];
    char* ldsa[4]; char* ldsbg[4]; char* ldsbu[4];
#pragma unroll
    for (int c = 0; c < 4; ++c) {
        int chunk = w * 4 + c;
        int row = chunk * 8 + lr8;          // tile-local row 0..127
        int r = rt * 128 + row;
        int tk;
        if (g == NEXP) tk = r;
        else           tk = (r < n_g) ? slot_token[sbase + r] : slot_token[sbase];
        aptr[c]  = (const char*)xb + ((size_t)tk * H_DIM) * 2 + swz;
        int nn   = dt * 128 + row;
        bgptr[c] = (const char*)Bg + ((size_t)nn * H_DIM) * 2 + swz;
        buptr[c] = (const char*)Bu + ((size_t)nn * H_DIM) * 2 + swz;
        ldsa[c]  = sA  + chunk * 1024;
        ldsbg[c] = sBg + chunk * 1024;
        ldsbu[c] = sBu + chunk * 1024;
    }

    f32x4 accg[4][4], accu[4][4];
#pragma unroll
    for (int m = 0; m < 4; ++m)
#pragma unroll
        for (int n = 0; n < 4; ++n) { accg[m][n] = 0.f; accu[m][n] = 0.f; }

    int wr = w >> 1, wc = w & 1;
    int lr = l & 15, lg = l >> 4;
    int rsw = (lr & 7) << 4;        // read-side swizzle (row&7 == lr&7 here)

    for (int ks = 0; ks < H_DIM / 64; ++ks) {
        int kb = ks * 128;
#pragma unroll
        for (int c = 0; c < 4; ++c) {
            gll16(aptr[c]  + kb, ldsa[c]);
            gll16(bgptr[c] + kb, ldsbg[c]);
            gll16(buptr[c] + kb, ldsbu[c]);
        }
        __syncthreads();
#pragma unroll
        for (int ksub = 0; ksub < 2; ++ksub) {
            int c0 = (ksub * 64 + lg * 16) ^ rsw;
            bf16x8 a[4], bg[4], bu[4];
#pragma unroll
            for (int m = 0; m < 4; ++m)
                a[m] = *(const bf16x8*)(sA + (wr * 64 + m * 16 + lr) * 128 + c0);
#pragma unroll
            for (int n = 0; n < 4; ++n) {
                bg[n] = *(const bf16x8*)(sBg + (wc * 64 + n * 16 + lr) * 128 + c0);
                bu[n] = *(const bf16x8*)(sBu + (wc * 64 + n * 16 + lr) * 128 + c0);
            }
#pragma unroll
            for (int m = 0; m < 4; ++m)
#pragma unroll
                for (int n = 0; n < 4; ++n) {
                    accg[m][n] = __builtin_amdgcn_mfma_f32_16x16x32_bf16(a[m], bg[n], accg[m][n], 0, 0, 0);
                    accu[m][n] = __builtin_amdgcn_mfma_f32_16x16x32_bf16(a[m], bu[n], accu[m][n], 0, 0, 0);
                }
        }
        __syncthreads();
    }

    int rb = rt * 128 + wr * 64;
    int cb = dt * 128 + wc * 64;
#pragma unroll
    for (int m = 0; m < 4; ++m)
#pragma unroll
        for (int n = 0; n < 4; ++n)
#pragma unroll
            for (int i = 0; i < 4; ++i) {
                int row = rb + m * 16 + lg * 4 + i;     // group-local row
                if (row < n_g) {
                    float gv = accg[m][n][i], uv = accu[m][n][i];
                    float hv = (gv / (1.f + __expf(-gv))) * uv;   // silu(g)*u
                    int col = cb + n * 16 + lr;
                    hid[(size_t)(hbase + row) * D_DIM + col] = f2bf(hv);
                }
            }
}

// ---------------- GEMM2: out = hid @ Wd^T; MODE 0 shared (store), MODE 1 routed (atomic) ----
template <int MODE>
__global__ __launch_bounds__(256) void k_gemm2(
    const unsigned short* __restrict__ hid,
    const unsigned short* __restrict__ wd_t, const unsigned short* __restrict__ wsd_t,
    const int* __restrict__ counts, const int* __restrict__ offs,
    const int* __restrict__ slot_token, const float* __restrict__ slot_weight,
    float* __restrict__ out) {
    int n_g, abase;
    const unsigned short* B;
    if (MODE == 0) { n_g = N_TOK; abase = SHARED_ROW; B = wsd_t; }
    else {
        int g = blockIdx.z;
        n_g = counts[g]; abase = offs[g];
        B = wd_t + (size_t)g * H_DIM * D_DIM;
    }
    int rt = blockIdx.y;
    if (rt * 128 >= n_g) return;
    int ct = blockIdx.x;

    __shared__ __attribute__((aligned(16))) char smem[32 * 1024];
    __shared__ int   sTok[128];
    __shared__ float sW[128];
    char* sA = smem; char* sB = smem + 16384;

    int t = threadIdx.x, w = t >> 6, l = t & 63;
    if (MODE == 1 && t < 128) {
        int r = rt * 128 + t;
        sTok[t] = (r < n_g) ? slot_token[abase + r]  : 0;
        sW[t]   = (r < n_g) ? slot_weight[abase + r] : 0.f;
    }
    int lr8 = l >> 3, lc8 = l & 7;
    int swz = ((lc8 ^ lr8) << 4);
    const char* aptr[4]; const char* bptr[4];
    char* ldsa[4]; char* ldsb[4];
#pragma unroll
    for (int c = 0; c < 4; ++c) {
        int chunk = w * 4 + c;
        int row = chunk * 8 + lr8;
        aptr[c] = (const char*)hid + ((size_t)(abase + rt * 128 + row) * D_DIM) * 2 + swz;
        int nn  = ct * 128 + row;
        bptr[c] = (const char*)B + ((size_t)nn * D_DIM) * 2 + swz;
        ldsa[c] = sA + chunk * 1024;
        ldsb[c] = sB + chunk * 1024;
    }
    f32x4 acc[4][4];
#pragma unroll
    for (int m = 0; m < 4; ++m)
#pragma unroll
        for (int n = 0; n < 4; ++n) acc[m][n] = 0.f;

    int wr = w >> 1, wc = w & 1, lr = l & 15, lg = l >> 4;
    int rsw = (lr & 7) << 4;

    for (int ks = 0; ks < D_DIM / 64; ++ks) {
        int kb = ks * 128;
#pragma unroll
        for (int c = 0; c < 4; ++c) {
            gll16(aptr[c] + kb, ldsa[c]);
            gll16(bptr[c] + kb, ldsb[c]);
        }
        __syncthreads();
#pragma unroll
        for (int ksub = 0; ksub < 2; ++ksub) {
            int c0 = (ksub * 64 + lg * 16) ^ rsw;
            bf16x8 a[4], b[4];
#pragma unroll
            for (int m = 0; m < 4; ++m)
                a[m] = *(const bf16x8*)(sA + (wr * 64 + m * 16 + lr) * 128 + c0);
#pragma unroll
            for (int n = 0; n < 4; ++n)
                b[n] = *(const bf16x8*)(sB + (wc * 64 + n * 16 + lr) * 128 + c0);
#pragma unroll
            for (int m = 0; m < 4; ++m)
#pragma unroll
                for (int n = 0; n < 4; ++n)
                    acc[m][n] = __builtin_amdgcn_mfma_f32_16x16x32_bf16(a[m], b[n], acc[m][n], 0, 0, 0);
        }
        __syncthreads();
    }

    int cb = ct * 128 + wc * 64;
#pragma unroll
    for (int m = 0; m < 4; ++m)
#pragma unroll
        for (int n = 0; n < 4; ++n)
#pragma unroll
            for (int i = 0; i < 4; ++i) {
                int tr = wr * 64 + m * 16 + lg * 4 + i;   // tile-local row
                int col = cb + n * 16 + lr;
                if (MODE == 0) {
                    out[(size_t)(rt * 128 + tr) * H_DIM + col] = acc[m][n][i];
                } else {
                    if (rt * 128 + tr < n_g) {
                        int tok = sTok[tr]; float wgt = sW[tr];
                        unsafeAtomicAdd(&out[(size_t)tok * H_DIM + col], acc[m][n][i] * wgt);
                    }
                }
            }
}

// ---------------- launch ----------------
extern "C" void kernel_launch(void* const* d_in, const int* in_sizes, int n_in,
                              void* d_out, int out_size, void* d_ws, size_t ws_size,
                              hipStream_t stream) {
    const float* x       = (const float*)d_in[0];
    const float* gw      = (const float*)d_in[1];
    const float* w_gate  = (const float*)d_in[2];
    const float* w_up    = (const float*)d_in[3];
    const float* w_down  = (const float*)d_in[4];
    const float* ws_gate = (const float*)d_in[5];
    const float* ws_up   = (const float*)d_in[6];
    const float* ws_down = (const float*)d_in[7];
    float* out = (float*)d_out;
    char* ws = (char*)d_ws;

    const size_t oXB    = 0;
    const size_t oWG    = oXB    + (size_t)N_TOK * H_DIM * 2;            // 16 MB
    const size_t oWU    = oWG    + (size_t)NEXP * D_DIM * H_DIM * 2;     // +32 MB
    const size_t oWD    = oWU    + (size_t)NEXP * D_DIM * H_DIM * 2;
    const size_t oWSG   = oWD    + (size_t)NEXP * H_DIM * D_DIM * 2;
    const size_t oWSU   = oWSG   + (size_t)D_DIM * H_DIM * 2;
    const size_t oWSD   = oWSU   + (size_t)D_DIM * H_DIM * 2;
    const size_t oHID   = oWSD   + (size_t)H_DIM * D_DIM * 2;
    const size_t oTOKE  = oHID   + (size_t)HID_ROWS * D_DIM * 2;
    const size_t oTOKW  = oTOKE  + (size_t)N_TOK * 2 * 4;
    const size_t oSLOTT = oTOKW  + (size_t)N_TOK * 2 * 4;
    const size_t oSLOTW = oSLOTT + (size_t)(NSLOT + 128) * 4;
    const size_t oCTRL  = oSLOTW + (size_t)(NSLOT + 128) * 4;

    unsigned short* xb    = (unsigned short*)(ws + oXB);
    unsigned short* wg_t  = (unsigned short*)(ws + oWG);
    unsigned short* wu_t  = (unsigned short*)(ws + oWU);
    unsigned short* wd_t  = (unsigned short*)(ws + oWD);
    unsigned short* wsg_t = (unsigned short*)(ws + oWSG);
    unsigned short* wsu_t = (unsigned short*)(ws + oWSU);
    unsigned short* wsd_t = (unsigned short*)(ws + oWSD);
    unsigned short* hid   = (unsigned short*)(ws + oHID);
    int*   tok_e       = (int*)(ws + oTOKE);
    float* tok_w       = (float*)(ws + oTOKW);
    int*   slot_token  = (int*)(ws + oSLOTT);
    float* slot_weight = (float*)(ws + oSLOTW);
    int*   counts      = (int*)(ws + oCTRL);
    int*   offs        = counts + 8;
    int*   cursor      = counts + 16;

    hipMemsetAsync(counts, 0, 256, stream);
    k_router<<<N_TOK / 4, 256, 0, stream>>>(x, gw, tok_e, tok_w, counts);
    k_scan<<<1, 64, 0, stream>>>(counts, offs);
    k_assign<<<N_TOK / 256, 256, 0, stream>>>(tok_e, tok_w, offs, cursor, slot_token, slot_weight);

    k_cvt_x<<<(N_TOK * H_DIM) / (8 * 256), 256, 0, stream>>>(x, xb);
    k_tconv<<<dim3(D_DIM / 32, H_DIM / 32, NEXP), 256, 0, stream>>>(w_gate, wg_t, H_DIM, D_DIM);
    k_tconv<<<dim3(D_DIM / 32, H_DIM / 32, NEXP), 256, 0, stream>>>(w_up,   wu_t, H_DIM, D_DIM);
    k_tconv<<<dim3(H_DIM / 32, D_DIM / 32, NEXP), 256, 0, stream>>>(w_down, wd_t, D_DIM, H_DIM);
    k_tconv<<<dim3(D_DIM / 32, H_DIM / 32, 1),    256, 0, stream>>>(ws_gate, wsg_t, H_DIM, D_DIM);
    k_tconv<<<dim3(D_DIM / 32, H_DIM / 32, 1),    256, 0, stream>>>(ws_up,   wsu_t, H_DIM, D_DIM);
    k_tconv<<<dim3(H_DIM / 32, D_DIM / 32, 1),    256, 0, stream>>>(ws_down, wsd_t, D_DIM, H_DIM);

    k_gemm1<<<dim3(16, 64, NEXP + 1), 256, 0, stream>>>(xb, wg_t, wu_t, wsg_t, wsu_t,
                                                        counts, offs, slot_token, hid);
    k_gemm2<0><<<dim3(8, 64, 1), 256, 0, stream>>>(hid, wd_t, wsd_t, counts, offs,
                                                   slot_token, slot_weight, out);
    k_gemm2<1><<<dim3(8, 64, NEXP), 256, 0, stream>>>(hid, wd_t, wsd_t, counts, offs,
                                                      slot_token, slot_weight, out);
}

// Round 2
// 928.980 us; speedup vs baseline: 1.3114x; 1.3114x over previous
//
#include <hip/hip_runtime.h>
#include <hip/hip_bf16.h>
#include <stdint.h>

#define N_TOK 8192
#define H_DIM 1024
#define D_DIM 2048
#define NEXP  8

#define NSLOT      16384          // N_TOK * 2 routed slots
#define SHARED_ROW 16512          // NSLOT + 128 pad rows
#define HID_ROWS   24704          // SHARED_ROW + N_TOK

typedef __attribute__((ext_vector_type(8))) short          bf16x8;
typedef __attribute__((ext_vector_type(4))) float          f32x4;
typedef __attribute__((ext_vector_type(8))) unsigned short u16x8;

__device__ __forceinline__ unsigned short f2bf(float f) {
    union { float f; uint32_t u; } v; v.f = f;
    uint32_t r = v.u + 0x7fff + ((v.u >> 16) & 1);   // RNE
    return (unsigned short)(r >> 16);
}

__device__ __forceinline__ void gll16(const void* g, void* l) {
    __builtin_amdgcn_global_load_lds(
        (const __attribute__((address_space(1))) void*)g,
        (__attribute__((address_space(3))) void*)l, 16, 0, 0);
}

// ---------------- router: one wave per token ----------------
__global__ void k_router(const float* __restrict__ x, const float* __restrict__ gw,
                         int* __restrict__ tok_e, float* __restrict__ tok_w,
                         int* __restrict__ counts) {
    int l = threadIdx.x & 63;
    int n = blockIdx.x * 4 + (threadIdx.x >> 6);
    const float* xr = x + (size_t)n * H_DIM + l * 16;
    float acc[NEXP];
#pragma unroll
    for (int e = 0; e < NEXP; ++e) acc[e] = 0.f;
#pragma unroll
    for (int j = 0; j < 16; ++j) {
        float xv = xr[j];
        const float4* g4 = (const float4*)(gw + (size_t)(l * 16 + j) * NEXP);
        float4 g0 = g4[0], g1 = g4[1];
        acc[0] += xv * g0.x; acc[1] += xv * g0.y; acc[2] += xv * g0.z; acc[3] += xv * g0.w;
        acc[4] += xv * g1.x; acc[5] += xv * g1.y; acc[6] += xv * g1.z; acc[7] += xv * g1.w;
    }
#pragma unroll
    for (int off = 32; off >= 1; off >>= 1) {
#pragma unroll
        for (int e = 0; e < NEXP; ++e) acc[e] += __shfl_xor(acc[e], off);
    }
    if (l == 0) {
        int e0 = 0; float v0 = acc[0];
#pragma unroll
        for (int e = 1; e < NEXP; ++e) if (acc[e] > v0) { v0 = acc[e]; e0 = e; }
        int e1 = -1; float v1 = -1e30f;
#pragma unroll
        for (int e = 0; e < NEXP; ++e) if (e != e0 && acc[e] > v1) { v1 = acc[e]; e1 = e; }
        float t  = expf(v1 - v0);          // p1/p0
        float w1 = t / (1.f + t);
        float w0 = 1.f - w1;
        tok_e[2 * n]     = e0;  tok_e[2 * n + 1] = e1;
        tok_w[2 * n]     = w0;  tok_w[2 * n + 1] = w1;
        atomicAdd(&counts[e0], 1);
        atomicAdd(&counts[e1], 1);
    }
}

__global__ void k_scan(const int* __restrict__ counts, int* __restrict__ offs) {
    if (threadIdx.x == 0) {
        int s = 0;
        for (int e = 0; e < NEXP; ++e) { offs[e] = s; s += counts[e]; }
    }
}

__global__ void k_assign(const int* __restrict__ tok_e, const float* __restrict__ tok_w,
                         const int* __restrict__ offs, int* __restrict__ cursor,
                         int* __restrict__ slot_token, float* __restrict__ slot_weight) {
    int n = blockIdx.x * 256 + threadIdx.x;
#pragma unroll
    for (int k = 0; k < 2; ++k) {
        int e   = tok_e[2 * n + k];
        float w = tok_w[2 * n + k];
        int pos = atomicAdd(&cursor[e], 1);
        int s   = offs[e] + pos;
        slot_token[s]  = n;
        slot_weight[s] = w;
    }
}

// ---------------- f32 -> bf16 convert (x) ----------------
__global__ void k_cvt_x(const float* __restrict__ x, unsigned short* __restrict__ xb) {
    size_t i = ((size_t)blockIdx.x * 256 + threadIdx.x) * 8;
    float4 a = *(const float4*)(x + i);
    float4 b = *(const float4*)(x + i + 4);
    u16x8 o;
    o[0] = f2bf(a.x); o[1] = f2bf(a.y); o[2] = f2bf(a.z); o[3] = f2bf(a.w);
    o[4] = f2bf(b.x); o[5] = f2bf(b.y); o[6] = f2bf(b.z); o[7] = f2bf(b.w);
    *(u16x8*)(xb + i) = o;
}

// ---------------- transpose + convert: src[R][C] f32 -> dst[C][R] bf16 ----------------
// 64x64 tile per block, float4 loads, u16x8 stores
__global__ void k_tconv(const float* __restrict__ src, unsigned short* __restrict__ dst,
                        int R, int C) {
    __shared__ float tb[64][65];
    size_t mb = (size_t)blockIdx.z * (size_t)R * C;
    src += mb; dst += mb;
    int t = threadIdx.x;
    int r0 = blockIdx.y * 64, c0 = blockIdx.x * 64;
    int c4 = t & 15, rr = t >> 4;           // 16 rows per pass
#pragma unroll
    for (int p = 0; p < 4; ++p) {
        int r = p * 16 + rr;
        float4 v = *(const float4*)(src + (size_t)(r0 + r) * C + c0 + c4 * 4);
        tb[r][c4 * 4 + 0] = v.x; tb[r][c4 * 4 + 1] = v.y;
        tb[r][c4 * 4 + 2] = v.z; tb[r][c4 * 4 + 3] = v.w;
    }
    __syncthreads();
    int rbase = (t & 7) * 8;
#pragma unroll
    for (int p = 0; p < 2; ++p) {
        int cc = p * 32 + (t >> 3);
        u16x8 o;
#pragma unroll
        for (int j = 0; j < 8; ++j) o[j] = f2bf(tb[rbase + j][cc]);
        *(u16x8*)(dst + (size_t)(c0 + cc) * R + r0 + rbase) = o;
    }
}

// ---------------- grouped GEMM1: hid = silu(A@Wg) * (A@Wu), A gathered ----------------
// tile 128(M) x 64(N), BK=64, 4 waves (2x2), per-wave 64x32 dual accumulator
// groups 0..7 routed (slot lists), group 8 = shared expert (identity rows)
__global__ __launch_bounds__(256, 3) void k_gemm1(
    const unsigned short* __restrict__ xb,
    const unsigned short* __restrict__ wg_t, const unsigned short* __restrict__ wu_t,
    const unsigned short* __restrict__ wsg_t, const unsigned short* __restrict__ wsu_t,
    const int* __restrict__ counts, const int* __restrict__ offs,
    const int* __restrict__ slot_token, unsigned short* __restrict__ hid) {
    int g = blockIdx.z;
    int n_g, sbase, hbase;
    if (g < NEXP) { n_g = counts[g]; sbase = offs[g]; hbase = sbase; }
    else          { n_g = N_TOK;     sbase = 0;       hbase = SHARED_ROW; }
    int rt = blockIdx.y;
    if (rt * 128 >= n_g) return;
    int dt = blockIdx.x;                     // 0..31 (N-tiles of 64)

    const unsigned short* Bg = (g < NEXP) ? wg_t + (size_t)g * D_DIM * H_DIM : wsg_t;
    const unsigned short* Bu = (g < NEXP) ? wu_t + (size_t)g * D_DIM * H_DIM : wsu_t;

    __shared__ __attribute__((aligned(16))) char smem[32 * 1024];
    char* sA  = smem;                        // 16 KB: 128 rows x 128 B
    char* sBg = smem + 16384;                //  8 KB:  64 rows x 128 B
    char* sBu = smem + 24576;                //  8 KB

    int t = threadIdx.x;
    int w = t >> 6, l = t & 63;
    int lr8 = l >> 3, lc8 = l & 7;
    int swz = ((lc8 ^ lr8) << 4);            // inverse-swizzled global source byte

    const char* aptr[4]; char* ldsa[4];
#pragma unroll
    for (int c = 0; c < 4; ++c) {            // A: 16 chunks of 1KB, wave w owns w*4+c
        int chunk = w * 4 + c;
        int row = chunk * 8 + lr8;           // 0..127
        int r = rt * 128 + row;
        int tk;
        if (g == NEXP) tk = r;
        else           tk = (r < n_g) ? slot_token[sbase + r] : slot_token[sbase];
        aptr[c] = (const char*)xb + ((size_t)tk * H_DIM) * 2 + swz;
        ldsa[c] = sA + chunk * 1024;
    }
    const char* bgptr[2]; const char* buptr[2]; char* ldsbg[2]; char* ldsbu[2];
#pragma unroll
    for (int c = 0; c < 2; ++c) {            // B: 8 chunks of 1KB each, wave w owns w*2+c
        int chunk = w * 2 + c;
        int row = chunk * 8 + lr8;           // 0..63
        int nn = dt * 64 + row;
        bgptr[c] = (const char*)Bg + ((size_t)nn * H_DIM) * 2 + swz;
        buptr[c] = (const char*)Bu + ((size_t)nn * H_DIM) * 2 + swz;
        ldsbg[c] = sBg + chunk * 1024;
        ldsbu[c] = sBu + chunk * 1024;
    }

    f32x4 accg[4][2], accu[4][2];
#pragma unroll
    for (int m = 0; m < 4; ++m)
#pragma unroll
        for (int n = 0; n < 2; ++n) { accg[m][n] = 0.f; accu[m][n] = 0.f; }

    int wr = w >> 1, wc = w & 1;
    int lr = l & 15, lg = l >> 4;
    int rsw = (lr & 7) << 4;                 // read-side swizzle

    for (int ks = 0; ks < H_DIM / 64; ++ks) {
        int kb = ks * 128;
#pragma unroll
        for (int c = 0; c < 4; ++c) gll16(aptr[c] + kb, ldsa[c]);
#pragma unroll
        for (int c = 0; c < 2; ++c) {
            gll16(bgptr[c] + kb, ldsbg[c]);
            gll16(buptr[c] + kb, ldsbu[c]);
        }
        __syncthreads();
#pragma unroll
        for (int ksub = 0; ksub < 2; ++ksub) {
            int c0 = (ksub * 64 + lg * 16) ^ rsw;
            bf16x8 a[4], bg[2], bu[2];
#pragma unroll
            for (int m = 0; m < 4; ++m)
                a[m] = *(const bf16x8*)(sA + (wr * 64 + m * 16 + lr) * 128 + c0);
#pragma unroll
            for (int n = 0; n < 2; ++n) {
                bg[n] = *(const bf16x8*)(sBg + (wc * 32 + n * 16 + lr) * 128 + c0);
                bu[n] = *(const bf16x8*)(sBu + (wc * 32 + n * 16 + lr) * 128 + c0);
            }
#pragma unroll
            for (int m = 0; m < 4; ++m)
#pragma unroll
                for (int n = 0; n < 2; ++n) {
                    accg[m][n] = __builtin_amdgcn_mfma_f32_16x16x32_bf16(a[m], bg[n], accg[m][n], 0, 0, 0);
                    accu[m][n] = __builtin_amdgcn_mfma_f32_16x16x32_bf16(a[m], bu[n], accu[m][n], 0, 0, 0);
                }
        }
        __syncthreads();
    }

    int cb = dt * 64 + wc * 32;
#pragma unroll
    for (int m = 0; m < 4; ++m)
#pragma unroll
        for (int n = 0; n < 2; ++n)
#pragma unroll
            for (int i = 0; i < 4; ++i) {
                int row = rt * 128 + wr * 64 + m * 16 + lg * 4 + i;   // group-local row
                if (row < n_g) {
                    float gv = accg[m][n][i], uv = accu[m][n][i];
                    float hv = (gv / (1.f + __expf(-gv))) * uv;       // silu(g)*u
                    int col = cb + n * 16 + lr;
                    hid[(size_t)(hbase + row) * D_DIM + col] = f2bf(hv);
                }
            }
}

// ---------------- GEMM2: out = hid @ Wd^T; MODE 0 shared (store), MODE 1 routed (atomic) ----
template <int MODE>
__global__ __launch_bounds__(256, 3) void k_gemm2(
    const unsigned short* __restrict__ hid,
    const unsigned short* __restrict__ wd_t, const unsigned short* __restrict__ wsd_t,
    const int* __restrict__ counts, const int* __restrict__ offs,
    const int* __restrict__ slot_token, const float* __restrict__ slot_weight,
    float* __restrict__ out) {
    int n_g, abase;
    const unsigned short* B;
    if (MODE == 0) { n_g = N_TOK; abase = SHARED_ROW; B = wsd_t; }
    else {
        int g = blockIdx.z;
        n_g = counts[g]; abase = offs[g];
        B = wd_t + (size_t)g * H_DIM * D_DIM;
    }
    int rt = blockIdx.y;
    if (rt * 128 >= n_g) return;
    int ct = blockIdx.x;

    __shared__ __attribute__((aligned(16))) char smem[32 * 1024];
    __shared__ int   sTok[128];
    __shared__ float sW[128];
    char* sA = smem; char* sB = smem + 16384;

    int t = threadIdx.x, w = t >> 6, l = t & 63;
    if (MODE == 1 && t < 128) {
        int r = rt * 128 + t;
        sTok[t] = (r < n_g) ? slot_token[abase + r]  : 0;
        sW[t]   = (r < n_g) ? slot_weight[abase + r] : 0.f;
    }
    int lr8 = l >> 3, lc8 = l & 7;
    int swz = ((lc8 ^ lr8) << 4);
    const char* aptr[4]; const char* bptr[4];
    char* ldsa[4]; char* ldsb[4];
#pragma unroll
    for (int c = 0; c < 4; ++c) {
        int chunk = w * 4 + c;
        int row = chunk * 8 + lr8;
        aptr[c] = (const char*)hid + ((size_t)(abase + rt * 128 + row) * D_DIM) * 2 + swz;
        int nn  = ct * 128 + row;
        bptr[c] = (const char*)B + ((size_t)nn * D_DIM) * 2 + swz;
        ldsa[c] = sA + chunk * 1024;
        ldsb[c] = sB + chunk * 1024;
    }
    f32x4 acc[4][4];
#pragma unroll
    for (int m = 0; m < 4; ++m)
#pragma unroll
        for (int n = 0; n < 4; ++n) acc[m][n] = 0.f;

    int wr = w >> 1, wc = w & 1, lr = l & 15, lg = l >> 4;
    int rsw = (lr & 7) << 4;

    for (int ks = 0; ks < D_DIM / 64; ++ks) {
        int kb = ks * 128;
#pragma unroll
        for (int c = 0; c < 4; ++c) {
            gll16(aptr[c] + kb, ldsa[c]);
            gll16(bptr[c] + kb, ldsb[c]);
        }
        __syncthreads();
#pragma unroll
        for (int ksub = 0; ksub < 2; ++ksub) {
            int c0 = (ksub * 64 + lg * 16) ^ rsw;
            bf16x8 a[4], b[4];
#pragma unroll
            for (int m = 0; m < 4; ++m)
                a[m] = *(const bf16x8*)(sA + (wr * 64 + m * 16 + lr) * 128 + c0);
#pragma unroll
            for (int n = 0; n < 4; ++n)
                b[n] = *(const bf16x8*)(sB + (wc * 64 + n * 16 + lr) * 128 + c0);
#pragma unroll
            for (int m = 0; m < 4; ++m)
#pragma unroll
                for (int n = 0; n < 4; ++n)
                    acc[m][n] = __builtin_amdgcn_mfma_f32_16x16x32_bf16(a[m], b[n], acc[m][n], 0, 0, 0);
        }
        __syncthreads();
    }

    int cb = ct * 128 + wc * 64;
#pragma unroll
    for (int m = 0; m < 4; ++m)
#pragma unroll
        for (int n = 0; n < 4; ++n)
#pragma unroll
            for (int i = 0; i < 4; ++i) {
                int tr = wr * 64 + m * 16 + lg * 4 + i;   // tile-local row
                int col = cb + n * 16 + lr;
                if (MODE == 0) {
                    out[(size_t)(rt * 128 + tr) * H_DIM + col] = acc[m][n][i];
                } else {
                    if (rt * 128 + tr < n_g) {
                        int tok = sTok[tr]; float wgt = sW[tr];
                        unsafeAtomicAdd(&out[(size_t)tok * H_DIM + col], acc[m][n][i] * wgt);
                    }
                }
            }
}

// ---------------- launch ----------------
extern "C" void kernel_launch(void* const* d_in, const int* in_sizes, int n_in,
                              void* d_out, int out_size, void* d_ws, size_t ws_size,
                              hipStream_t stream) {
    const float* x       = (const float*)d_in[0];
    const float* gw      = (const float*)d_in[1];
    const float* w_gate  = (const float*)d_in[2];
    const float* w_up    = (const float*)d_in[3];
    const float* w_down  = (const float*)d_in[4];
    const float* ws_gate = (const float*)d_in[5];
    const float* ws_up   = (const float*)d_in[6];
    const float* ws_down = (const float*)d_in[7];
    float* out = (float*)d_out;
    char* ws = (char*)d_ws;

    const size_t oXB    = 0;
    const size_t oWG    = oXB    + (size_t)N_TOK * H_DIM * 2;            // 16 MB
    const size_t oWU    = oWG    + (size_t)NEXP * D_DIM * H_DIM * 2;     // +32 MB
    const size_t oWD    = oWU    + (size_t)NEXP * D_DIM * H_DIM * 2;
    const size_t oWSG   = oWD    + (size_t)NEXP * H_DIM * D_DIM * 2;
    const size_t oWSU   = oWSG   + (size_t)D_DIM * H_DIM * 2;
    const size_t oWSD   = oWSU   + (size_t)D_DIM * H_DIM * 2;
    const size_t oHID   = oWSD   + (size_t)H_DIM * D_DIM * 2;
    const size_t oTOKE  = oHID   + (size_t)HID_ROWS * D_DIM * 2;
    const size_t oTOKW  = oTOKE  + (size_t)N_TOK * 2 * 4;
    const size_t oSLOTT = oTOKW  + (size_t)N_TOK * 2 * 4;
    const size_t oSLOTW = oSLOTT + (size_t)(NSLOT + 128) * 4;
    const size_t oCTRL  = oSLOTW + (size_t)(NSLOT + 128) * 4;

    unsigned short* xb    = (unsigned short*)(ws + oXB);
    unsigned short* wg_t  = (unsigned short*)(ws + oWG);
    unsigned short* wu_t  = (unsigned short*)(ws + oWU);
    unsigned short* wd_t  = (unsigned short*)(ws + oWD);
    unsigned short* wsg_t = (unsigned short*)(ws + oWSG);
    unsigned short* wsu_t = (unsigned short*)(ws + oWSU);
    unsigned short* wsd_t = (unsigned short*)(ws + oWSD);
    unsigned short* hid   = (unsigned short*)(ws + oHID);
    int*   tok_e       = (int*)(ws + oTOKE);
    float* tok_w       = (float*)(ws + oTOKW);
    int*   slot_token  = (int*)(ws + oSLOTT);
    float* slot_weight = (float*)(ws + oSLOTW);
    int*   counts      = (int*)(ws + oCTRL);
    int*   offs        = counts + 8;
    int*   cursor      = counts + 16;

    hipMemsetAsync(counts, 0, 256, stream);
    k_router<<<N_TOK / 4, 256, 0, stream>>>(x, gw, tok_e, tok_w, counts);
    k_scan<<<1, 64, 0, stream>>>(counts, offs);
    k_assign<<<N_TOK / 256, 256, 0, stream>>>(tok_e, tok_w, offs, cursor, slot_token, slot_weight);

    k_cvt_x<<<(N_TOK * H_DIM) / (8 * 256), 256, 0, stream>>>(x, xb);
    k_tconv<<<dim3(D_DIM / 64, H_DIM / 64, NEXP), 256, 0, stream>>>(w_gate, wg_t, H_DIM, D_DIM);
    k_tconv<<<dim3(D_DIM / 64, H_DIM / 64, NEXP), 256, 0, stream>>>(w_up,   wu_t, H_DIM, D_DIM);
    k_tconv<<<dim3(H_DIM / 64, D_DIM / 64, NEXP), 256, 0, stream>>>(w_down, wd_t, D_DIM, H_DIM);
    k_tconv<<<dim3(D_DIM / 64, H_DIM / 64, 1),    256, 0, stream>>>(ws_gate, wsg_t, H_DIM, D_DIM);
    k_tconv<<<dim3(D_DIM / 64, H_DIM / 64, 1),    256, 0, stream>>>(ws_up,   wsu_t, H_DIM, D_DIM);
    k_tconv<<<dim3(H_DIM / 64, D_DIM / 64, 1),    256, 0, stream>>>(ws_down, wsd_t, D_DIM, H_DIM);

    k_gemm1<<<dim3(32, 64, NEXP + 1), 256, 0, stream>>>(xb, wg_t, wu_t, wsg_t, wsu_t,
                                                        counts, offs, slot_token, hid);
    k_gemm2<0><<<dim3(8, 64, 1), 256, 0, stream>>>(hid, wd_t, wsd_t, counts, offs,
                                                   slot_token, slot_weight, out);
    k_gemm2<1><<<dim3(8, 64, NEXP), 256, 0, stream>>>(hid, wd_t, wsd_t, counts, offs,
                                                      slot_token, slot_weight, out);
}